// Round 12
// baseline (798.792 us; speedup 1.0000x reference)
//
#include <hip/hip_runtime.h>
#include <cstdint>
#include <cstddef>

#define NB 128
#define NT 512
#define NJ 21
#define NC 3
#define NH 64
#define JH 1344   // NJ*NH
#define G3 192    // 3*NH
#define OUT0 (NB*NJ*NC) // 8064
#define FB 4      // frames per k1 block (one per wave)

typedef __attribute__((ext_vector_type(8))) __bf16 bf16x8;
typedef __attribute__((ext_vector_type(4))) float f32x4;

__device__ __forceinline__ float bf2f(unsigned short u) {
  union { unsigned int i; float f; } v; v.i = ((unsigned int)u) << 16; return v.f;
}
__device__ __forceinline__ unsigned short f2bf(float f) {
  union { float f; unsigned int i; } v; v.f = f;
  unsigned int x = v.i;
  unsigned int lsb = (x >> 16) & 1u;
  x += 0x7fffu + lsb;
  return (unsigned short)(x >> 16);
}
__device__ __forceinline__ unsigned int pk_bf16(float lo, float hi) {
  unsigned int r;
  asm("v_cvt_pk_bf16_f32 %0, %1, %2" : "=v"(r) : "v"(lo), "v"(hi));
  return r;
}
__device__ __forceinline__ unsigned int scale2(unsigned int u, float s) {
  float lo = __uint_as_float(u << 16);
  float hi = __uint_as_float(u & 0xffff0000u);
  return pk_bf16(lo * s, hi * s);
}

// ---------------- K0: convert W_ih (192x1344 f32) to bf16
__global__ __launch_bounds__(256) void k0_convw(
    const float* __restrict__ W, unsigned short* __restrict__ Wbf) {
  const int ti = blockIdx.x*256 + threadIdx.x;
  const float4 v = ((const float4*)W)[ti];
  uint2 o;
  o.x = (unsigned int)f2bf(v.x) | ((unsigned int)f2bf(v.y) << 16);
  o.y = (unsigned int)f2bf(v.z) | ((unsigned int)f2bf(v.w) << 16);
  ((uint2*)Wbf)[ti] = o;
}

// ---------------- K1: fused GCN x2 via MFMA, linear padded LDS (unchanged)
__global__ __launch_bounds__(256, 2) void k1_fused(
    const float* __restrict__ x, const float* __restrict__ A,
    const float* __restrict__ W1, const float* __restrict__ b1,
    const float* __restrict__ W2, const float* __restrict__ b2,
    const float* __restrict__ Wa,
    unsigned short* __restrict__ h2out, float* __restrict__ scorepart) {
  __shared__ unsigned short h1s[FB*32*72];
  __shared__ unsigned short us[FB*64*40];
  __shared__ unsigned short w2s[64*72];
  __shared__ unsigned short adjs[32*40];
  __shared__ unsigned short h2st[FB*NJ*72];
  __shared__ float afs[NJ*NJ];
  __shared__ float xs[4][64];
  __shared__ float ags[4][64];
  __shared__ float spred[4][NJ];

  const int tid = threadIdx.x;
  const int w = tid >> 6, l = tid & 63;
  const int q = l >> 4, r = l & 15;
  const int b = blockIdx.x >> 7, ch = blockIdx.x & 127;
  const int t0 = ch * FB;

  for (int i = tid; i < NJ*NJ; i += 256) afs[i] = A[i];
  for (int i = tid; i < 1024; i += 256) {
    const int ii = i >> 5, jj = i & 31;
    adjs[ii*40 + jj] = (ii < NJ && jj < NJ) ? f2bf(A[ii*NJ + jj]) : (unsigned short)0;
  }
  {
    const int h = tid & 63, qd = tid >> 6;
    const int g0 = qd * 16;
#pragma unroll
    for (int e = 0; e < 16; e += 2) {
      const float v0 = W2[h*64 + g0 + e], v1 = W2[h*64 + g0 + e + 1];
      ((unsigned int*)w2s)[h*36 + ((g0 + e) >> 1)] = pk_bf16(v0, v1);
    }
  }
#pragma unroll
  for (int j = NJ; j < 32; ++j)
    ((unsigned int*)h1s)[(w*32 + j)*36 + (l & 31)] = 0u;

  const float w1r0 = W1[l*3+0], w1r1 = W1[l*3+1], w1r2 = W1[l*3+2];
  const float b1h = b1[l];
  float b2v[4][4], wav[4][4];
#pragma unroll
  for (int mt = 0; mt < 4; ++mt)
#pragma unroll
    for (int rg = 0; rg < 4; ++rg) {
      const int h = mt*16 + q*4 + rg;
      b2v[mt][rg] = b2[h]; wav[mt][rg] = Wa[h];
    }
  __syncthreads();   // B0

  {
    const size_t fr = (size_t)(b*NT + t0 + w);
    if (l < NJ*NC) xs[w][l] = x[fr*(NJ*NC) + l];
    if (l < NJ*NC) {
      const int ji = l / 3, c = l - ji*3;
      float s = 0.f;
#pragma unroll
      for (int j = 0; j < NJ; ++j) s += afs[ji*NJ + j] * xs[w][j*3 + c];
      ags[w][l] = s;
    }
#pragma unroll
    for (int j = 0; j < NJ; ++j) {
      float v = b1h + w1r0*ags[w][j*3+0] + w1r1*ags[w][j*3+1] + w1r2*ags[w][j*3+2];
      v = fmaxf(v, 0.f);
      h1s[(w*32 + j)*72 + l] = f2bf(v);
    }
  }
  __syncthreads();   // B1

  bf16x8 bw[2][4];
#pragma unroll
  for (int ks = 0; ks < 2; ++ks)
#pragma unroll
    for (int nt = 0; nt < 4; ++nt)
      bw[ks][nt] = *(const bf16x8*)(&w2s[(nt*16 + r)*72 + (ks*4 + q)*8]);
  f32x4 acc1[2][4];
#pragma unroll
  for (int i = 0; i < 2; ++i)
#pragma unroll
    for (int j2 = 0; j2 < 4; ++j2) acc1[i][j2] = (f32x4)0.f;
#pragma unroll
  for (int mti = 0; mti < 2; ++mti) {
    const int row = (w*2 + mti)*16 + r;
#pragma unroll
    for (int ks = 0; ks < 2; ++ks) {
      const bf16x8 af = *(const bf16x8*)(&h1s[row*72 + (ks*4 + q)*8]);
#pragma unroll
      for (int nt = 0; nt < 4; ++nt)
        acc1[mti][nt] = __builtin_amdgcn_mfma_f32_16x16x32_bf16(af, bw[ks][nt], acc1[mti][nt], 0,0,0);
    }
  }
#pragma unroll
  for (int mti = 0; mti < 2; ++mti)
#pragma unroll
    for (int nt = 0; nt < 4; ++nt) {
      const int h = nt*16 + r;
#pragma unroll
      for (int rp = 0; rp < 2; ++rp) {
        const int jp = mti*16 + q*4 + rp*2;
        ((unsigned int*)us)[(w*64 + h)*20 + (jp >> 1)] =
            pk_bf16(acc1[mti][nt][rp*2], acc1[mti][nt][rp*2+1]);
      }
    }
  __syncthreads();   // B2

  bf16x8 badj[2];
#pragma unroll
  for (int nt = 0; nt < 2; ++nt)
    badj[nt] = *(const bf16x8*)(&adjs[(nt*16 + r)*40 + q*8]);
  f32x4 acc2[4][2];
#pragma unroll
  for (int i = 0; i < 4; ++i) { acc2[i][0] = (f32x4)0.f; acc2[i][1] = (f32x4)0.f; }
#pragma unroll
  for (int mt = 0; mt < 4; ++mt) {
    const int h = mt*16 + r;
    const bf16x8 af = *(const bf16x8*)(&us[(w*64 + h)*40 + q*8]);
#pragma unroll
    for (int nt = 0; nt < 2; ++nt)
      acc2[mt][nt] = __builtin_amdgcn_mfma_f32_16x16x32_bf16(af, badj[nt], acc2[mt][nt], 0,0,0);
  }
  float sp0 = 0.f, sp1 = 0.f;
#pragma unroll
  for (int nt = 0; nt < 2; ++nt) {
    const int i = nt*16 + r;
    if (i < NJ) {
#pragma unroll
      for (int mt = 0; mt < 4; ++mt)
#pragma unroll
        for (int rp = 0; rp < 2; ++rp) {
          const int h0 = mt*16 + q*4 + rp*2;
          const float v0 = fmaxf(acc2[mt][nt][rp*2]   + b2v[mt][rp*2],   0.f);
          const float v1 = fmaxf(acc2[mt][nt][rp*2+1] + b2v[mt][rp*2+1], 0.f);
          if (nt == 0) sp0 += v0*wav[mt][rp*2] + v1*wav[mt][rp*2+1];
          else         sp1 += v0*wav[mt][rp*2] + v1*wav[mt][rp*2+1];
          ((unsigned int*)h2st)[(w*NJ + i)*36 + (h0 >> 1)] = pk_bf16(v0, v1);
        }
    }
  }
  sp0 += __shfl_xor(sp0, 16); sp0 += __shfl_xor(sp0, 32);
  sp1 += __shfl_xor(sp1, 16); sp1 += __shfl_xor(sp1, 32);
  if (l < 16) spred[w][l] = sp0;
  if (l < 5)  spred[w][16 + l] = sp1;
  __syncthreads();   // B3

  if (tid < NJ)
    scorepart[((size_t)b*128 + ch)*NJ + tid] =
      spred[0][tid] + spred[1][tid] + spred[2][tid] + spred[3][tid];

  const size_t gbase = (size_t)(b*NT + t0) * JH;
  for (int cid = tid; cid < FB*NJ*8; cid += 256) {
    const int f = cid / (NJ*8), rem = cid - f*(NJ*8);
    const int i = rem >> 3, p = rem & 7;
    const uint4 v = *(const uint4*)(&h2st[(f*NJ + i)*72 + p*8]);
    *(uint4*)(&h2out[gbase + (size_t)f*JH + i*64 + p*8]) = v;
  }
}

// ---------------- K2: reduce score partials, softmax over joints
__global__ __launch_bounds__(64) void k2_attn(
    const float* __restrict__ scorepart, float* __restrict__ attn,
    float* __restrict__ out_attn) {
  __shared__ float ss[NJ];
  const int b = blockIdx.x, tid = threadIdx.x;
  if (tid < NJ) {
    float s = 0.f;
    for (int ch = 0; ch < 128; ++ch) s += scorepart[(b*128 + ch)*NJ + tid];
    ss[tid] = s * (1.0f/NT);
  }
  __syncthreads();
  float m = -1e30f;
  for (int j = 0; j < NJ; ++j) m = fmaxf(m, ss[j]);
  float sum = 0.f;
  for (int j = 0; j < NJ; ++j) sum += expf(ss[j] - m);
  if (tid < NJ) {
    float a = expf(ss[tid] - m) / sum;
    attn[b*NJ + tid] = a;
    out_attn[b*NJ + tid] = a;
  }
}

// ---------------- K3: xproj^T = (h2 * attn) @ W_ih.T + bias  -- MFMA bf16
__global__ __launch_bounds__(256, 2) void k3_xproj_mfma(
    const unsigned short* __restrict__ h2, const unsigned short* __restrict__ Wbf,
    const float* __restrict__ b_ih, const float* __restrict__ b_hh,
    const float* __restrict__ attn, float* __restrict__ xproj) {
  __shared__ unsigned short Abuf[2][128*32];
  __shared__ unsigned short Bbuf[2][192*32];
  const int tid = threadIdx.x;
  const int w = tid >> 6, l = tid & 63;
  const int lq = l >> 4, lr = l & 15;
  const int blk = blockIdx.x;
  const int b = blk >> 2;
  const int t0 = (blk & 3) << 7;
  const int wm = w >> 1, wn = w & 1;

  const unsigned short* gA[2]; int ldsA[2];
#pragma unroll
  for (int i = 0; i < 2; ++i) {
    const int lc = tid*2 + i, rr = lc >> 2, j = lc & 3;
    gA[i] = h2 + (size_t)(b*NT + t0 + rr)*JH + j*8;
    ldsA[i] = rr*32 + ((j ^ ((rr>>1)&3)) << 3);
  }
  const unsigned short* gB[3]; int ldsB[3];
#pragma unroll
  for (int i = 0; i < 3; ++i) {
    const int lc = tid + 256*i, g = lc >> 2, j = lc & 3;
    gB[i] = Wbf + (size_t)g*JH + j*8;
    ldsB[i] = g*32 + ((j ^ ((g>>1)&3)) << 3);
  }
  int aoff[4], boff[6];
#pragma unroll
  for (int mt = 0; mt < 4; ++mt) {
    const int row = wm*64 + mt*16 + lr;
    aoff[mt] = row*32 + ((lq ^ ((row>>1)&3)) << 3);
  }
#pragma unroll
  for (int nt = 0; nt < 6; ++nt) {
    const int g = wn*96 + nt*16 + lr;
    boff[nt] = g*32 + ((lq ^ ((g>>1)&3)) << 3);
  }

  f32x4 acc[4][6];
#pragma unroll
  for (int mt = 0; mt < 4; ++mt)
#pragma unroll
    for (int nt = 0; nt < 6; ++nt) acc[mt][nt] = (f32x4)0.f;

  {
    const float s = attn[b*NJ + 0];
#pragma unroll
    for (int i = 0; i < 2; ++i)
      *(uint4*)(&Abuf[0][ldsA[i]]) = *(const uint4*)(gA[i]);
#pragma unroll
    for (int i = 0; i < 3; ++i) {
      uint4 v = *(const uint4*)(gB[i]);
      v.x = scale2(v.x, s); v.y = scale2(v.y, s);
      v.z = scale2(v.z, s); v.w = scale2(v.w, s);
      *(uint4*)(&Bbuf[0][ldsB[i]]) = v;
    }
  }
  __syncthreads();

  for (int ks = 0; ks < 42; ++ks) {
    const int cur = ks & 1;
    uint4 av0, av1, bv0, bv1, bv2;
    if (ks < 41) {
      const int kk = (ks+1)*32;
      av0 = *(const uint4*)(gA[0] + kk);
      av1 = *(const uint4*)(gA[1] + kk);
      bv0 = *(const uint4*)(gB[0] + kk);
      bv1 = *(const uint4*)(gB[1] + kk);
      bv2 = *(const uint4*)(gB[2] + kk);
    }
    bf16x8 af[4], bfr[6];
#pragma unroll
    for (int mt = 0; mt < 4; ++mt) af[mt] = *(const bf16x8*)(&Abuf[cur][aoff[mt]]);
#pragma unroll
    for (int nt = 0; nt < 6; ++nt) bfr[nt] = *(const bf16x8*)(&Bbuf[cur][boff[nt]]);
#pragma unroll
    for (int mt = 0; mt < 4; ++mt)
#pragma unroll
      for (int nt = 0; nt < 6; ++nt)
        acc[mt][nt] = __builtin_amdgcn_mfma_f32_16x16x32_bf16(af[mt], bfr[nt], acc[mt][nt], 0, 0, 0);
    if (ks < 41) {
      const float s = attn[b*NJ + ((ks+1) >> 1)];
      *(uint4*)(&Abuf[cur^1][ldsA[0]]) = av0;
      *(uint4*)(&Abuf[cur^1][ldsA[1]]) = av1;
      uint4 v;
      v = bv0; v.x = scale2(v.x, s); v.y = scale2(v.y, s); v.z = scale2(v.z, s); v.w = scale2(v.w, s);
      *(uint4*)(&Bbuf[cur^1][ldsB[0]]) = v;
      v = bv1; v.x = scale2(v.x, s); v.y = scale2(v.y, s); v.z = scale2(v.z, s); v.w = scale2(v.w, s);
      *(uint4*)(&Bbuf[cur^1][ldsB[1]]) = v;
      v = bv2; v.x = scale2(v.x, s); v.y = scale2(v.y, s); v.z = scale2(v.z, s); v.w = scale2(v.w, s);
      *(uint4*)(&Bbuf[cur^1][ldsB[2]]) = v;
    }
    __syncthreads();
  }

  float bias[6];
#pragma unroll
  for (int nt = 0; nt < 6; ++nt) {
    const int g = wn*96 + nt*16 + lr;
    bias[nt] = b_ih[g] + (g < 2*NH ? b_hh[g] : 0.f);
  }
#pragma unroll
  for (int mt = 0; mt < 4; ++mt)
#pragma unroll
    for (int nt = 0; nt < 6; ++nt) {
      const int g = wn*96 + nt*16 + lr;
      const int trow = t0 + wm*64 + mt*16 + lq*4;
      float4 o;
      o.x = acc[mt][nt][0] + bias[nt];
      o.y = acc[mt][nt][1] + bias[nt];
      o.z = acc[mt][nt][2] + bias[nt];
      o.w = acc[mt][nt][3] + bias[nt];
      *(float4*)(&xproj[(size_t)(b*G3 + g)*NT + trow]) = o;
    }
}

// ---------------- K4: MFMA GRU v6 — TWO independent batch-groups per block
// interleaved in one barrier interval. Group A = batches b0..b0+15, group B =
// b0+16..b0+31 (grid 4 x 512thr). Both groups advance one step per barrier;
// A's LDS/MFMA latency overlaps B's gate math and vice versa, halving the
// per-step sync/latency overhead that dominates (R9-R11: 1368 cyc/step vs
// ~420 of issue). Per-group structure byte-identical to proven R9 kernel:
// lane-linear hb4, packed ds_write_b32, T4 lgkmcnt-only drain + raw barrier.
__global__ __launch_bounds__(512, 1) void k4_gru_mfma(
    const float* __restrict__ xproj, const float* __restrict__ W_hh,
    const float* __restrict__ b_hh, float* __restrict__ hT) {
  __shared__ __align__(16) uint4 hbA[2][2][4][16];  // 4 KB
  __shared__ __align__(16) uint4 hbB[2][2][4][16];  // 4 KB
  const int tid = threadIdx.x;
  const int w = tid >> 6, l = tid & 63, q = l >> 4, r15 = l & 15;
  const int b0 = blockIdx.x * 32;

  for (int i = tid; i < 256; i += 512) {
    ((uint4*)hbA)[i] = uint4{0u,0u,0u,0u};
    ((uint4*)hbB)[i] = uint4{0u,0u,0u,0u};
  }

  // A-frags: Wg rows permuted so lane (w,q,r15) owns ADJACENT channels
  // {8w+2q, 8w+2q+1}; shared by both groups.
  bf16x8 afr[2][2];
  int chv[2]; float bn_[2];
#pragma unroll
  for (int i = 0; i < 2; ++i) {
    const int mt = 2*w + i;
    const int gate = r15 & 3;
    const int cha = 8*(mt >> 1) + 2*(r15 >> 2) + (mt & 1);  // A-side channel
#pragma unroll
    for (int ks = 0; ks < 2; ++ks) {
      union { bf16x8 v; unsigned int u[4]; } tu;
      if (gate < 3) {
        const float* src = W_hh + (size_t)(gate*NH + cha)*NH + ks*32 + q*8;
        const float4 a = *(const float4*)(src);
        const float4 b = *(const float4*)(src + 4);
        tu.u[0] = pk_bf16(a.x, a.y); tu.u[1] = pk_bf16(a.z, a.w);
        tu.u[2] = pk_bf16(b.x, b.y); tu.u[3] = pk_bf16(b.z, b.w);
      } else {
        tu.u[0]=0u; tu.u[1]=0u; tu.u[2]=0u; tu.u[3]=0u;
      }
      afr[i][ks] = tu.v;
    }
    chv[i] = 8*w + 2*q + i;   // D-side channel this lane owns
    bn_[i] = b_hh[2*NH + chv[i]];
  }
  const int half = w >> 2, qblk = w & 3;

  const float* xrowA[2][3]; const float* xrowB[2][3];
#pragma unroll
  for (int i = 0; i < 2; ++i)
#pragma unroll
    for (int e = 0; e < 3; ++e) {
      xrowA[i][e] = xproj + (size_t)((b0 + r15)*G3 + e*NH + chv[i]) * NT;
      xrowB[i][e] = xproj + (size_t)((b0 + 16 + r15)*G3 + e*NH + chv[i]) * NT;
    }

  float hpA[2] = {0.f, 0.f}, hpB[2] = {0.f, 0.f};
  __syncthreads();   // once: zero-init visible (full drain OK here)

  f32x4 curA[2][3], nxtA[2][3], curB[2][3], nxtB[2][3];
#pragma unroll
  for (int i = 0; i < 2; ++i)
#pragma unroll
    for (int e = 0; e < 3; ++e) {
      curA[i][e] = *(const f32x4*)(xrowA[i][e]); nxtA[i][e] = curA[i][e];
      curB[i][e] = *(const f32x4*)(xrowB[i][e]); nxtB[i][e] = curB[i][e];
    }

  for (int tg = 0; tg < NT; tg += 4) {
    if (tg + 4 < NT) {
#pragma unroll
      for (int i = 0; i < 2; ++i)
#pragma unroll
        for (int e = 0; e < 3; ++e) {
          nxtA[i][e] = *(const f32x4*)(xrowA[i][e] + tg + 4);
          nxtB[i][e] = *(const f32x4*)(xrowB[i][e] + tg + 4);
        }
    }
#pragma unroll
    for (int p = 0; p < 4; ++p) {
      const int rb = p & 1, wb = rb ^ 1;
      const bf16x8 a0 = *(const bf16x8*)(&hbA[rb][0][q][r15]);
      const bf16x8 a1 = *(const bf16x8*)(&hbA[rb][1][q][r15]);
      const bf16x8 b0v = *(const bf16x8*)(&hbB[rb][0][q][r15]);
      const bf16x8 b1v = *(const bf16x8*)(&hbB[rb][1][q][r15]);
      f32x4 accA[2], accB[2];
      accA[0] = (f32x4)0.f; accA[1] = (f32x4)0.f;
      accB[0] = (f32x4)0.f; accB[1] = (f32x4)0.f;
      accA[0] = __builtin_amdgcn_mfma_f32_16x16x32_bf16(afr[0][0], a0, accA[0], 0,0,0);
      accA[1] = __builtin_amdgcn_mfma_f32_16x16x32_bf16(afr[1][0], a0, accA[1], 0,0,0);
      accB[0] = __builtin_amdgcn_mfma_f32_16x16x32_bf16(afr[0][0], b0v, accB[0], 0,0,0);
      accB[1] = __builtin_amdgcn_mfma_f32_16x16x32_bf16(afr[1][0], b0v, accB[1], 0,0,0);
      accA[0] = __builtin_amdgcn_mfma_f32_16x16x32_bf16(afr[0][1], a1, accA[0], 0,0,0);
      accA[1] = __builtin_amdgcn_mfma_f32_16x16x32_bf16(afr[1][1], a1, accA[1], 0,0,0);
      accB[0] = __builtin_amdgcn_mfma_f32_16x16x32_bf16(afr[0][1], b1v, accB[0], 0,0,0);
      accB[1] = __builtin_amdgcn_mfma_f32_16x16x32_bf16(afr[1][1], b1v, accB[1], 0,0,0);
      float hnA[2], hnB[2];
#pragma unroll
      for (int i = 0; i < 2; ++i) {
        {
          const float xr = curA[i][0][p], xz = curA[i][1][p], xn = curA[i][2][p];
          const float hn = accA[i][2] + bn_[i];
          const float rr = __builtin_amdgcn_rcpf(1.f + __expf(-(xr + accA[i][0])));
          const float zz = __builtin_amdgcn_rcpf(1.f + __expf(-(xz + accA[i][1])));
          const float nx = xn + rr*hn;
          const float nn = 2.f*__builtin_amdgcn_rcpf(1.f + __expf(-2.f*nx)) - 1.f;
          hnA[i] = nn + zz*(hpA[i] - nn);
          hpA[i] = hnA[i];
        }
        {
          const float xr = curB[i][0][p], xz = curB[i][1][p], xn = curB[i][2][p];
          const float hn = accB[i][2] + bn_[i];
          const float rr = __builtin_amdgcn_rcpf(1.f + __expf(-(xr + accB[i][0])));
          const float zz = __builtin_amdgcn_rcpf(1.f + __expf(-(xz + accB[i][1])));
          const float nx = xn + rr*hn;
          const float nn = 2.f*__builtin_amdgcn_rcpf(1.f + __expf(-2.f*nx)) - 1.f;
          hnB[i] = nn + zz*(hpB[i] - nn);
          hpB[i] = hnB[i];
        }
      }
      ((unsigned int*)&hbA[wb][half][qblk][r15])[q] = pk_bf16(hnA[0], hnA[1]);
      ((unsigned int*)&hbB[wb][half][qblk][r15])[q] = pk_bf16(hnB[0], hnB[1]);
      // T4: LDS-only drain + raw barrier -> global prefetch stays in flight
      asm volatile("s_waitcnt lgkmcnt(0)" ::: "memory");
      __builtin_amdgcn_s_barrier();
    }
#pragma unroll
    for (int i = 0; i < 2; ++i)
#pragma unroll
      for (int e = 0; e < 3; ++e) {
        curA[i][e] = nxtA[i][e];
        curB[i][e] = nxtB[i][e];
      }
  }

#pragma unroll
  for (int i = 0; i < 2; ++i) {
    hT[(size_t)(b0 + r15)*NH + chv[i]]      = hpA[i];
    hT[(size_t)(b0 + 16 + r15)*NH + chv[i]] = hpB[i];
  }
}

// ---------------- K5: head
__global__ __launch_bounds__(256) void k5_head(
    const float* __restrict__ hT, const float* __restrict__ W_head,
    const float* __restrict__ b_head, float* __restrict__ out) {
  const int idx = blockIdx.x*256 + threadIdx.x;
  if (idx >= NB*63) return;
  const int b = idx / 63, rr = idx % 63;
  const float* hv = hT + b*NH;
  const float* wr = W_head + rr*NH;
  float acc = b_head[rr];
#pragma unroll
  for (int k = 0; k < NH; ++k) acc += hv[k]*wr[k];
  out[idx] = acc;
}

extern "C" void kernel_launch(void* const* d_in, const int* in_sizes, int n_in,
                              void* d_out, int out_size, void* d_ws, size_t ws_size,
                              hipStream_t stream) {
  const float* x      = (const float*)d_in[0];
  const float* A      = (const float*)d_in[1];
  const float* W1     = (const float*)d_in[2];
  const float* b1     = (const float*)d_in[3];
  const float* W2     = (const float*)d_in[4];
  const float* b2     = (const float*)d_in[5];
  const float* Wa     = (const float*)d_in[6];
  // d_in[7] = ba : softmax-invariant, unused
  const float* W_ih   = (const float*)d_in[8];
  const float* b_ih   = (const float*)d_in[9];
  const float* W_hh   = (const float*)d_in[10];
  const float* b_hh   = (const float*)d_in[11];
  const float* W_head = (const float*)d_in[12];
  const float* b_head = (const float*)d_in[13];
  float* out = (float*)d_out;

  char* ws = (char*)d_ws;
  size_t off = 0;
  unsigned short* h2 = (unsigned short*)(ws + off); off += (size_t)NB*NT*JH*2;   // 176 MB
  float* scorepart   = (float*)(ws + off);          off += (size_t)NB*128*NJ*4;  // 1.38 MB
  float* attn        = (float*)(ws + off);          off += (size_t)NB*NJ*4;
  off = (off + 15) & ~(size_t)15;
  float* xproj       = (float*)(ws + off);          off += (size_t)NB*NT*G3*4;   // 50 MB, [b][g][t]
  float* hT          = (float*)(ws + off);          off += (size_t)NB*NH*4;
  off = (off + 15) & ~(size_t)15;
  unsigned short* Wbf = (unsigned short*)(ws + off); off += (size_t)G3*JH*2;     // 516 KB

  k0_convw<<<dim3(252),       256, 0, stream>>>(W_ih, Wbf);
  k1_fused<<<dim3(NB*128),    256, 0, stream>>>(x, A, W1, b1, W2, b2, Wa, h2, scorepart);
  k2_attn<<<dim3(NB),          64, 0, stream>>>(scorepart, attn, out + OUT0);
  k3_xproj_mfma<<<dim3(512),  256, 0, stream>>>(h2, Wbf, b_ih, b_hh, attn, xproj);
  k4_gru_mfma<<<dim3(4),      512, 0, stream>>>(xproj, W_hh, b_hh, hT);
  k5_head<<<dim3((NB*63 + 255)/256), 256, 0, stream>>>(hT, W_head, b_head, out);
}

// Round 13
// 495.091 us; speedup vs baseline: 1.6134x; 1.6134x over previous
//
#include <hip/hip_runtime.h>
#include <cstdint>
#include <cstddef>

#define NB 128
#define NT 512
#define NJ 21
#define NC 3
#define NH 64
#define JH 1344   // NJ*NH
#define G3 192    // 3*NH
#define OUT0 (NB*NJ*NC) // 8064
#define FB 4      // frames per k1 block (one per wave)

typedef __attribute__((ext_vector_type(8))) __bf16 bf16x8;
typedef __attribute__((ext_vector_type(4))) float f32x4;

__device__ __forceinline__ float bf2f(unsigned short u) {
  union { unsigned int i; float f; } v; v.i = ((unsigned int)u) << 16; return v.f;
}
__device__ __forceinline__ unsigned short f2bf(float f) {
  union { float f; unsigned int i; } v; v.f = f;
  unsigned int x = v.i;
  unsigned int lsb = (x >> 16) & 1u;
  x += 0x7fffu + lsb;
  return (unsigned short)(x >> 16);
}
__device__ __forceinline__ unsigned int pk_bf16(float lo, float hi) {
  unsigned int r;
  asm("v_cvt_pk_bf16_f32 %0, %1, %2" : "=v"(r) : "v"(lo), "v"(hi));
  return r;
}
__device__ __forceinline__ unsigned int scale2(unsigned int u, float s) {
  float lo = __uint_as_float(u << 16);
  float hi = __uint_as_float(u & 0xffff0000u);
  return pk_bf16(lo * s, hi * s);
}

// ---------------- K0: convert W_ih (192x1344 f32) to bf16
__global__ __launch_bounds__(256) void k0_convw(
    const float* __restrict__ W, unsigned short* __restrict__ Wbf) {
  const int ti = blockIdx.x*256 + threadIdx.x;
  const float4 v = ((const float4*)W)[ti];
  uint2 o;
  o.x = (unsigned int)f2bf(v.x) | ((unsigned int)f2bf(v.y) << 16);
  o.y = (unsigned int)f2bf(v.z) | ((unsigned int)f2bf(v.w) << 16);
  ((uint2*)Wbf)[ti] = o;
}

// ---------------- K1: fused GCN x2 via MFMA, linear padded LDS (unchanged)
__global__ __launch_bounds__(256, 2) void k1_fused(
    const float* __restrict__ x, const float* __restrict__ A,
    const float* __restrict__ W1, const float* __restrict__ b1,
    const float* __restrict__ W2, const float* __restrict__ b2,
    const float* __restrict__ Wa,
    unsigned short* __restrict__ h2out, float* __restrict__ scorepart) {
  __shared__ unsigned short h1s[FB*32*72];
  __shared__ unsigned short us[FB*64*40];
  __shared__ unsigned short w2s[64*72];
  __shared__ unsigned short adjs[32*40];
  __shared__ unsigned short h2st[FB*NJ*72];
  __shared__ float afs[NJ*NJ];
  __shared__ float xs[4][64];
  __shared__ float ags[4][64];
  __shared__ float spred[4][NJ];

  const int tid = threadIdx.x;
  const int w = tid >> 6, l = tid & 63;
  const int q = l >> 4, r = l & 15;
  const int b = blockIdx.x >> 7, ch = blockIdx.x & 127;
  const int t0 = ch * FB;

  for (int i = tid; i < NJ*NJ; i += 256) afs[i] = A[i];
  for (int i = tid; i < 1024; i += 256) {
    const int ii = i >> 5, jj = i & 31;
    adjs[ii*40 + jj] = (ii < NJ && jj < NJ) ? f2bf(A[ii*NJ + jj]) : (unsigned short)0;
  }
  {
    const int h = tid & 63, qd = tid >> 6;
    const int g0 = qd * 16;
#pragma unroll
    for (int e = 0; e < 16; e += 2) {
      const float v0 = W2[h*64 + g0 + e], v1 = W2[h*64 + g0 + e + 1];
      ((unsigned int*)w2s)[h*36 + ((g0 + e) >> 1)] = pk_bf16(v0, v1);
    }
  }
#pragma unroll
  for (int j = NJ; j < 32; ++j)
    ((unsigned int*)h1s)[(w*32 + j)*36 + (l & 31)] = 0u;

  const float w1r0 = W1[l*3+0], w1r1 = W1[l*3+1], w1r2 = W1[l*3+2];
  const float b1h = b1[l];
  float b2v[4][4], wav[4][4];
#pragma unroll
  for (int mt = 0; mt < 4; ++mt)
#pragma unroll
    for (int rg = 0; rg < 4; ++rg) {
      const int h = mt*16 + q*4 + rg;
      b2v[mt][rg] = b2[h]; wav[mt][rg] = Wa[h];
    }
  __syncthreads();   // B0

  {
    const size_t fr = (size_t)(b*NT + t0 + w);
    if (l < NJ*NC) xs[w][l] = x[fr*(NJ*NC) + l];
    if (l < NJ*NC) {
      const int ji = l / 3, c = l - ji*3;
      float s = 0.f;
#pragma unroll
      for (int j = 0; j < NJ; ++j) s += afs[ji*NJ + j] * xs[w][j*3 + c];
      ags[w][l] = s;
    }
#pragma unroll
    for (int j = 0; j < NJ; ++j) {
      float v = b1h + w1r0*ags[w][j*3+0] + w1r1*ags[w][j*3+1] + w1r2*ags[w][j*3+2];
      v = fmaxf(v, 0.f);
      h1s[(w*32 + j)*72 + l] = f2bf(v);
    }
  }
  __syncthreads();   // B1

  bf16x8 bw[2][4];
#pragma unroll
  for (int ks = 0; ks < 2; ++ks)
#pragma unroll
    for (int nt = 0; nt < 4; ++nt)
      bw[ks][nt] = *(const bf16x8*)(&w2s[(nt*16 + r)*72 + (ks*4 + q)*8]);
  f32x4 acc1[2][4];
#pragma unroll
  for (int i = 0; i < 2; ++i)
#pragma unroll
    for (int j2 = 0; j2 < 4; ++j2) acc1[i][j2] = (f32x4)0.f;
#pragma unroll
  for (int mti = 0; mti < 2; ++mti) {
    const int row = (w*2 + mti)*16 + r;
#pragma unroll
    for (int ks = 0; ks < 2; ++ks) {
      const bf16x8 af = *(const bf16x8*)(&h1s[row*72 + (ks*4 + q)*8]);
#pragma unroll
      for (int nt = 0; nt < 4; ++nt)
        acc1[mti][nt] = __builtin_amdgcn_mfma_f32_16x16x32_bf16(af, bw[ks][nt], acc1[mti][nt], 0,0,0);
    }
  }
#pragma unroll
  for (int mti = 0; mti < 2; ++mti)
#pragma unroll
    for (int nt = 0; nt < 4; ++nt) {
      const int h = nt*16 + r;
#pragma unroll
      for (int rp = 0; rp < 2; ++rp) {
        const int jp = mti*16 + q*4 + rp*2;
        ((unsigned int*)us)[(w*64 + h)*20 + (jp >> 1)] =
            pk_bf16(acc1[mti][nt][rp*2], acc1[mti][nt][rp*2+1]);
      }
    }
  __syncthreads();   // B2

  bf16x8 badj[2];
#pragma unroll
  for (int nt = 0; nt < 2; ++nt)
    badj[nt] = *(const bf16x8*)(&adjs[(nt*16 + r)*40 + q*8]);
  f32x4 acc2[4][2];
#pragma unroll
  for (int i = 0; i < 4; ++i) { acc2[i][0] = (f32x4)0.f; acc2[i][1] = (f32x4)0.f; }
#pragma unroll
  for (int mt = 0; mt < 4; ++mt) {
    const int h = mt*16 + r;
    const bf16x8 af = *(const bf16x8*)(&us[(w*64 + h)*40 + q*8]);
#pragma unroll
    for (int nt = 0; nt < 2; ++nt)
      acc2[mt][nt] = __builtin_amdgcn_mfma_f32_16x16x32_bf16(af, badj[nt], acc2[mt][nt], 0,0,0);
  }
  float sp0 = 0.f, sp1 = 0.f;
#pragma unroll
  for (int nt = 0; nt < 2; ++nt) {
    const int i = nt*16 + r;
    if (i < NJ) {
#pragma unroll
      for (int mt = 0; mt < 4; ++mt)
#pragma unroll
        for (int rp = 0; rp < 2; ++rp) {
          const int h0 = mt*16 + q*4 + rp*2;
          const float v0 = fmaxf(acc2[mt][nt][rp*2]   + b2v[mt][rp*2],   0.f);
          const float v1 = fmaxf(acc2[mt][nt][rp*2+1] + b2v[mt][rp*2+1], 0.f);
          if (nt == 0) sp0 += v0*wav[mt][rp*2] + v1*wav[mt][rp*2+1];
          else         sp1 += v0*wav[mt][rp*2] + v1*wav[mt][rp*2+1];
          ((unsigned int*)h2st)[(w*NJ + i)*36 + (h0 >> 1)] = pk_bf16(v0, v1);
        }
    }
  }
  sp0 += __shfl_xor(sp0, 16); sp0 += __shfl_xor(sp0, 32);
  sp1 += __shfl_xor(sp1, 16); sp1 += __shfl_xor(sp1, 32);
  if (l < 16) spred[w][l] = sp0;
  if (l < 5)  spred[w][16 + l] = sp1;
  __syncthreads();   // B3

  if (tid < NJ)
    scorepart[((size_t)b*128 + ch)*NJ + tid] =
      spred[0][tid] + spred[1][tid] + spred[2][tid] + spred[3][tid];

  const size_t gbase = (size_t)(b*NT + t0) * JH;
  for (int cid = tid; cid < FB*NJ*8; cid += 256) {
    const int f = cid / (NJ*8), rem = cid - f*(NJ*8);
    const int i = rem >> 3, p = rem & 7;
    const uint4 v = *(const uint4*)(&h2st[(f*NJ + i)*72 + p*8]);
    *(uint4*)(&h2out[gbase + (size_t)f*JH + i*64 + p*8]) = v;
  }
}

// ---------------- K2: reduce score partials, softmax over joints
__global__ __launch_bounds__(64) void k2_attn(
    const float* __restrict__ scorepart, float* __restrict__ attn,
    float* __restrict__ out_attn) {
  __shared__ float ss[NJ];
  const int b = blockIdx.x, tid = threadIdx.x;
  if (tid < NJ) {
    float s = 0.f;
    for (int ch = 0; ch < 128; ++ch) s += scorepart[(b*128 + ch)*NJ + tid];
    ss[tid] = s * (1.0f/NT);
  }
  __syncthreads();
  float m = -1e30f;
  for (int j = 0; j < NJ; ++j) m = fmaxf(m, ss[j]);
  float sum = 0.f;
  for (int j = 0; j < NJ; ++j) sum += expf(ss[j] - m);
  if (tid < NJ) {
    float a = expf(ss[tid] - m) / sum;
    attn[b*NJ + tid] = a;
    out_attn[b*NJ + tid] = a;
  }
}

// ---------------- K3: xproj^T = (h2 * attn) @ W_ih.T + bias  -- MFMA bf16
__global__ __launch_bounds__(256, 2) void k3_xproj_mfma(
    const unsigned short* __restrict__ h2, const unsigned short* __restrict__ Wbf,
    const float* __restrict__ b_ih, const float* __restrict__ b_hh,
    const float* __restrict__ attn, float* __restrict__ xproj) {
  __shared__ unsigned short Abuf[2][128*32];
  __shared__ unsigned short Bbuf[2][192*32];
  const int tid = threadIdx.x;
  const int w = tid >> 6, l = tid & 63;
  const int lq = l >> 4, lr = l & 15;
  const int blk = blockIdx.x;
  const int b = blk >> 2;
  const int t0 = (blk & 3) << 7;
  const int wm = w >> 1, wn = w & 1;

  const unsigned short* gA[2]; int ldsA[2];
#pragma unroll
  for (int i = 0; i < 2; ++i) {
    const int lc = tid*2 + i, rr = lc >> 2, j = lc & 3;
    gA[i] = h2 + (size_t)(b*NT + t0 + rr)*JH + j*8;
    ldsA[i] = rr*32 + ((j ^ ((rr>>1)&3)) << 3);
  }
  const unsigned short* gB[3]; int ldsB[3];
#pragma unroll
  for (int i = 0; i < 3; ++i) {
    const int lc = tid + 256*i, g = lc >> 2, j = lc & 3;
    gB[i] = Wbf + (size_t)g*JH + j*8;
    ldsB[i] = g*32 + ((j ^ ((g>>1)&3)) << 3);
  }
  int aoff[4], boff[6];
#pragma unroll
  for (int mt = 0; mt < 4; ++mt) {
    const int row = wm*64 + mt*16 + lr;
    aoff[mt] = row*32 + ((lq ^ ((row>>1)&3)) << 3);
  }
#pragma unroll
  for (int nt = 0; nt < 6; ++nt) {
    const int g = wn*96 + nt*16 + lr;
    boff[nt] = g*32 + ((lq ^ ((g>>1)&3)) << 3);
  }

  f32x4 acc[4][6];
#pragma unroll
  for (int mt = 0; mt < 4; ++mt)
#pragma unroll
    for (int nt = 0; nt < 6; ++nt) acc[mt][nt] = (f32x4)0.f;

  {
    const float s = attn[b*NJ + 0];
#pragma unroll
    for (int i = 0; i < 2; ++i)
      *(uint4*)(&Abuf[0][ldsA[i]]) = *(const uint4*)(gA[i]);
#pragma unroll
    for (int i = 0; i < 3; ++i) {
      uint4 v = *(const uint4*)(gB[i]);
      v.x = scale2(v.x, s); v.y = scale2(v.y, s);
      v.z = scale2(v.z, s); v.w = scale2(v.w, s);
      *(uint4*)(&Bbuf[0][ldsB[i]]) = v;
    }
  }
  __syncthreads();

  for (int ks = 0; ks < 42; ++ks) {
    const int cur = ks & 1;
    uint4 av0, av1, bv0, bv1, bv2;
    if (ks < 41) {
      const int kk = (ks+1)*32;
      av0 = *(const uint4*)(gA[0] + kk);
      av1 = *(const uint4*)(gA[1] + kk);
      bv0 = *(const uint4*)(gB[0] + kk);
      bv1 = *(const uint4*)(gB[1] + kk);
      bv2 = *(const uint4*)(gB[2] + kk);
    }
    bf16x8 af[4], bfr[6];
#pragma unroll
    for (int mt = 0; mt < 4; ++mt) af[mt] = *(const bf16x8*)(&Abuf[cur][aoff[mt]]);
#pragma unroll
    for (int nt = 0; nt < 6; ++nt) bfr[nt] = *(const bf16x8*)(&Bbuf[cur][boff[nt]]);
#pragma unroll
    for (int mt = 0; mt < 4; ++mt)
#pragma unroll
      for (int nt = 0; nt < 6; ++nt)
        acc[mt][nt] = __builtin_amdgcn_mfma_f32_16x16x32_bf16(af[mt], bfr[nt], acc[mt][nt], 0, 0, 0);
    if (ks < 41) {
      const float s = attn[b*NJ + ((ks+1) >> 1)];
      *(uint4*)(&Abuf[cur^1][ldsA[0]]) = av0;
      *(uint4*)(&Abuf[cur^1][ldsA[1]]) = av1;
      uint4 v;
      v = bv0; v.x = scale2(v.x, s); v.y = scale2(v.y, s); v.z = scale2(v.z, s); v.w = scale2(v.w, s);
      *(uint4*)(&Bbuf[cur^1][ldsB[0]]) = v;
      v = bv1; v.x = scale2(v.x, s); v.y = scale2(v.y, s); v.z = scale2(v.z, s); v.w = scale2(v.w, s);
      *(uint4*)(&Bbuf[cur^1][ldsB[1]]) = v;
      v = bv2; v.x = scale2(v.x, s); v.y = scale2(v.y, s); v.z = scale2(v.z, s); v.w = scale2(v.w, s);
      *(uint4*)(&Bbuf[cur^1][ldsB[2]]) = v;
    }
    __syncthreads();
  }

  float bias[6];
#pragma unroll
  for (int nt = 0; nt < 6; ++nt) {
    const int g = wn*96 + nt*16 + lr;
    bias[nt] = b_ih[g] + (g < 2*NH ? b_hh[g] : 0.f);
  }
#pragma unroll
  for (int mt = 0; mt < 4; ++mt)
#pragma unroll
    for (int nt = 0; nt < 6; ++nt) {
      const int g = wn*96 + nt*16 + lr;
      const int trow = t0 + wm*64 + mt*16 + lq*4;
      float4 o;
      o.x = acc[mt][nt][0] + bias[nt];
      o.y = acc[mt][nt][1] + bias[nt];
      o.z = acc[mt][nt][2] + bias[nt];
      o.w = acc[mt][nt][3] + bias[nt];
      *(float4*)(&xproj[(size_t)(b*G3 + g)*NT + trow]) = o;
    }
}

// ---------------- K4: MFMA GRU v7 — 16 waves x ONE m-tile each (1024 thr,
// grid 8, 16 batches/block). R12 showed per-step time scales with per-WAVE
// stream length (2x work -> exactly 2x time, per-CU VALUBusy unchanged); this
// halves the per-wave stream vs R9: 2 MFMA (was 4), 1 channel of gate math
// (was 2), one ds_write_b16 (paired waves fill the two bytes of each dword).
// Consumer-side lane-linear hb4 layout and T4 barrier structure unchanged.
// Per-SIMD work is unchanged (4 waves x 1/2 work) -> clean discriminator.
__global__ __launch_bounds__(1024, 1) void k4_gru_mfma(
    const float* __restrict__ xproj, const float* __restrict__ W_hh,
    const float* __restrict__ b_hh, float* __restrict__ hT) {
  __shared__ __align__(16) uint4 hb4[2][2][4][16];  // 4 KB
  const int tid = threadIdx.x;
  const int w = tid >> 6, l = tid & 63, q = l >> 4, r15 = l & 15;
  const int b0 = blockIdx.x * 16;

  for (int i = tid; i < 256; i += 1024) ((uint4*)hb4)[i] = uint4{0u,0u,0u,0u};

  // A-frags for tile mt = w: lane (q,r15) holds A[row=r15][k=ks*32+q*8+e].
  // Row r15 of tile w -> (cha = 8*(w>>1)+2*(r15>>2)+(w&1), gate = r15&3).
  bf16x8 afr[2];
  const int gate = r15 & 3;
  const int cha = 8*(w >> 1) + 2*(r15 >> 2) + (w & 1);
#pragma unroll
  for (int ks = 0; ks < 2; ++ks) {
    union { bf16x8 v; unsigned int u[4]; } tu;
    if (gate < 3) {
      const float* src = W_hh + (size_t)(gate*NH + cha)*NH + ks*32 + q*8;
      const float4 a = *(const float4*)(src);
      const float4 b = *(const float4*)(src + 4);
      tu.u[0] = pk_bf16(a.x, a.y); tu.u[1] = pk_bf16(a.z, a.w);
      tu.u[2] = pk_bf16(b.x, b.y); tu.u[3] = pk_bf16(b.z, b.w);
    } else {
      tu.u[0]=0u; tu.u[1]=0u; tu.u[2]=0u; tu.u[3]=0u;
    }
    afr[ks] = tu.v;
  }
  // D-side: lane (q,r15) owns channel chv (rows q*4+{0,1,2} of tile w = gates
  // r/z/n of chv), batch r15. Its write slot: word q, byte-half (w&1) of
  // hb4[wb][w>>3][(w>>1)&3][r15] (lane-linear consumer layout preserved).
  const int chv = 8*(w >> 1) + 2*q + (w & 1);
  const float bn_ = b_hh[2*NH + chv];
  const int wh = w >> 3, wq = (w >> 1) & 3, wb16 = q*2 + (w & 1);

  const float* xrow[3];
#pragma unroll
  for (int e = 0; e < 3; ++e)
    xrow[e] = xproj + (size_t)((b0 + r15)*G3 + e*NH + chv) * NT;

  float hprev = 0.f;
  __syncthreads();   // once: hb4 zero-init visible (full drain OK here)

  f32x4 cur[3], nxt[3];
#pragma unroll
  for (int e = 0; e < 3; ++e) { cur[e] = *(const f32x4*)(xrow[e]); nxt[e] = cur[e]; }

  for (int tg = 0; tg < NT; tg += 4) {
    if (tg + 4 < NT) {
#pragma unroll
      for (int e = 0; e < 3; ++e) nxt[e] = *(const f32x4*)(xrow[e] + tg + 4);
    }
#pragma unroll
    for (int p = 0; p < 4; ++p) {
      const int rb = p & 1, wbuf = rb ^ 1;
      const bf16x8 bh0 = *(const bf16x8*)(&hb4[rb][0][q][r15]);
      const bf16x8 bh1 = *(const bf16x8*)(&hb4[rb][1][q][r15]);
      f32x4 acc = (f32x4)0.f;
      acc = __builtin_amdgcn_mfma_f32_16x16x32_bf16(afr[0], bh0, acc, 0,0,0);
      acc = __builtin_amdgcn_mfma_f32_16x16x32_bf16(afr[1], bh1, acc, 0,0,0);
      const float xr = cur[0][p], xz = cur[1][p], xn = cur[2][p];
      const float hn = acc[2] + bn_;
      const float rr = __builtin_amdgcn_rcpf(1.f + __expf(-(xr + acc[0])));
      const float zz = __builtin_amdgcn_rcpf(1.f + __expf(-(xz + acc[1])));
      const float nx = xn + rr*hn;
      const float nn = 2.f*__builtin_amdgcn_rcpf(1.f + __expf(-2.f*nx)) - 1.f;
      const float hnew = nn + zz*(hprev - nn);
      hprev = hnew;
      ((unsigned short*)&hb4[wbuf][wh][wq][r15])[wb16] = f2bf(hnew);
      // T4: LDS-only drain + raw barrier -> global prefetch stays in flight
      asm volatile("s_waitcnt lgkmcnt(0)" ::: "memory");
      __builtin_amdgcn_s_barrier();
    }
#pragma unroll
    for (int e = 0; e < 3; ++e) cur[e] = nxt[e];
  }

  hT[(size_t)(b0 + r15)*NH + chv] = hprev;
}

// ---------------- K5: head
__global__ __launch_bounds__(256) void k5_head(
    const float* __restrict__ hT, const float* __restrict__ W_head,
    const float* __restrict__ b_head, float* __restrict__ out) {
  const int idx = blockIdx.x*256 + threadIdx.x;
  if (idx >= NB*63) return;
  const int b = idx / 63, rr = idx % 63;
  const float* hv = hT + b*NH;
  const float* wr = W_head + rr*NH;
  float acc = b_head[rr];
#pragma unroll
  for (int k = 0; k < NH; ++k) acc += hv[k]*wr[k];
  out[idx] = acc;
}

extern "C" void kernel_launch(void* const* d_in, const int* in_sizes, int n_in,
                              void* d_out, int out_size, void* d_ws, size_t ws_size,
                              hipStream_t stream) {
  const float* x      = (const float*)d_in[0];
  const float* A      = (const float*)d_in[1];
  const float* W1     = (const float*)d_in[2];
  const float* b1     = (const float*)d_in[3];
  const float* W2     = (const float*)d_in[4];
  const float* b2     = (const float*)d_in[5];
  const float* Wa     = (const float*)d_in[6];
  // d_in[7] = ba : softmax-invariant, unused
  const float* W_ih   = (const float*)d_in[8];
  const float* b_ih   = (const float*)d_in[9];
  const float* W_hh   = (const float*)d_in[10];
  const float* b_hh   = (const float*)d_in[11];
  const float* W_head = (const float*)d_in[12];
  const float* b_head = (const float*)d_in[13];
  float* out = (float*)d_out;

  char* ws = (char*)d_ws;
  size_t off = 0;
  unsigned short* h2 = (unsigned short*)(ws + off); off += (size_t)NB*NT*JH*2;   // 176 MB
  float* scorepart   = (float*)(ws + off);          off += (size_t)NB*128*NJ*4;  // 1.38 MB
  float* attn        = (float*)(ws + off);          off += (size_t)NB*NJ*4;
  off = (off + 15) & ~(size_t)15;
  float* xproj       = (float*)(ws + off);          off += (size_t)NB*NT*G3*4;   // 50 MB, [b][g][t]
  float* hT          = (float*)(ws + off);          off += (size_t)NB*NH*4;
  off = (off + 15) & ~(size_t)15;
  unsigned short* Wbf = (unsigned short*)(ws + off); off += (size_t)G3*JH*2;     // 516 KB

  k0_convw<<<dim3(252),       256, 0, stream>>>(W_ih, Wbf);
  k1_fused<<<dim3(NB*128),    256, 0, stream>>>(x, A, W1, b1, W2, b2, Wa, h2, scorepart);
  k2_attn<<<dim3(NB),          64, 0, stream>>>(scorepart, attn, out + OUT0);
  k3_xproj_mfma<<<dim3(512),  256, 0, stream>>>(h2, Wbf, b_ih, b_hh, attn, xproj);
  k4_gru_mfma<<<dim3(8),     1024, 0, stream>>>(xproj, W_hh, b_hh, hT);
  k5_head<<<dim3((NB*63 + 255)/256), 256, 0, stream>>>(hT, W_head, b_head, out);
}